// Round 2
// baseline (59.872 us; speedup 1.0000x reference)
//
#include <hip/hip_runtime.h>
#include <hip/hip_cooperative_groups.h>
#include <math.h>

namespace cg = cooperative_groups;

#define BB 2
#define SS 256
#define DD 256
#define EPSF 1e-6f

// ---- wave(64)-level primitives ----
__device__ __forceinline__ float wave_sum(float v) {
#pragma unroll
    for (int o = 32; o > 0; o >>= 1) v += __shfl_xor(v, o);
    return v;
}

__device__ __forceinline__ float block_sum(float v, float* lds) {
    const int t = threadIdx.x, w = t >> 6, lane = t & 63;
    v = wave_sum(v);
    if (lane == 0) lds[w] = v;
    __syncthreads();
    float r = lds[0] + lds[1] + lds[2] + lds[3];
    __syncthreads();
    return r;
}

// returns {sum(a), sum(b)} across block
__device__ __forceinline__ float2 block_sum2(float a, float b, float* lds) {
    const int t = threadIdx.x, w = t >> 6, lane = t & 63;
    a = wave_sum(a);
    b = wave_sum(b);
    if (lane == 0) { lds[w] = a; lds[4 + w] = b; }
    __syncthreads();
    float2 r;
    r.x = lds[0] + lds[1] + lds[2] + lds[3];
    r.y = lds[4] + lds[5] + lds[6] + lds[7];
    __syncthreads();
    return r;
}

__device__ __forceinline__ float wave_scan_sum(float v) {
    const int lane = threadIdx.x & 63;
#pragma unroll
    for (int o = 1; o < 64; o <<= 1) {
        float u = __shfl_up(v, o);
        if (lane >= o) v += u;
    }
    return v;
}

__device__ __forceinline__ float wave_scan_prod(float v) {
    const int lane = threadIdx.x & 63;
#pragma unroll
    for (int o = 1; o < 64; o <<= 1) {
        float u = __shfl_up(v, o);
        if (lane >= o) v *= u;
    }
    return v;
}

// inclusive block-wide sum scan (256 threads = 4 waves)
__device__ __forceinline__ float block_scan_sum(float v, float* lds) {
    const int t = threadIdx.x, w = t >> 6, lane = t & 63;
    v = wave_scan_sum(v);
    if (lane == 63) lds[w] = v;
    __syncthreads();
    float pre = 0.0f;
#pragma unroll
    for (int j = 0; j < 3; ++j)
        if (w > j) pre += lds[j];
    __syncthreads();
    return v + pre;
}

// inclusive block-wide product scan
__device__ __forceinline__ float block_scan_prod(float v, float* lds) {
    const int t = threadIdx.x, w = t >> 6, lane = t & 63;
    v = wave_scan_prod(v);
    if (lane == 63) lds[w] = v;
    __syncthreads();
    float pre = 1.0f;
#pragma unroll
    for (int j = 0; j < 3; ++j)
        if (w > j) pre *= lds[j];
    __syncthreads();
    return v * pre;
}

__global__ void fused_kernel(const float* __restrict__ ctx,
                             const float* __restrict__ ln_g,
                             const float* __restrict__ ln_b,
                             const float* __restrict__ fc_w,
                             const float* __restrict__ prior,
                             const float* __restrict__ fc_b,
                             float* __restrict__ G,
                             float* __restrict__ Mij,
                             float* __restrict__ dx1,
                             float* __restrict__ dx2) {
    __shared__ float lds[SS];           // reused: reductions, scans, incl-store
    const int r = blockIdx.x;           // b*S + row
    const int t = threadIdx.x;

    // ---- Phase A: LayerNorm + dots for row r ----
    const float c  = ctx[r * DD + t];
    const float mu = block_sum(c, lds) * (1.0f / DD);
    const float dmu = c - mu;
    const float var = block_sum(dmu * dmu, lds) * (1.0f / (DD - 1));
    const float xn = ln_g[t] * dmu / (sqrtf(var) + EPSF) + ln_b[t];
    const float2 s = block_sum2(xn * fc_w[t], xn * fc_w[DD + t], lds);
    if (t == 0) { dx1[r] = s.x; dx2[r] = s.y; }

    cg::this_grid().sync();

    // ---- Phase B: Mij + product scan -> symmetric G, row i of batch b ----
    const int b = r >> 8, i = r & 255, k = t;
    const float pr = prior[0], fb = fc_b[0];

    // inclusive prefix sums of dx2 for this batch (recomputed per block; L2-hit)
    const float d2 = dx2[b * SS + k];
    const float incl = block_scan_sum(d2, lds);
    lds[k] = incl;                       // store for indexed read
    __syncthreads();
    const float base = (i > 0) ? lds[i - 1] : 0.0f;
    __syncthreads();

    float m;
    if (k >= i) {
        const float l = dx1[b * SS + k] + (incl - base) / (float)(k - i + 1) + fb;
        m = pr + (1.0f - pr) / (1.0f + expf(-l));
    } else {
        m = pr + (1.0f - pr) / (1.0f + expf(-fb));
    }
    Mij[r * SS + k] = m;

    const float v = (k >= i) ? m : 1.0f;
    const float p = block_scan_prod(v, lds);

    if (k == i) {
        G[(b * SS + i) * SS + i] = 1.0f;
    } else if (k > i) {
        G[(b * SS + i) * SS + k] = p;     // row (upper triangle)
        G[(b * SS + k) * SS + i] = p;     // symmetric element
    }
}

extern "C" void kernel_launch(void* const* d_in, const int* in_sizes, int n_in,
                              void* d_out, int out_size, void* d_ws, size_t ws_size,
                              hipStream_t stream) {
    const float* ctx   = (const float*)d_in[0];
    // d_in[1] = eos_mask (unused by reference)
    const float* prior = (const float*)d_in[2];
    const float* ln_g  = (const float*)d_in[3];
    const float* ln_b  = (const float*)d_in[4];
    const float* fc_w  = (const float*)d_in[5];
    const float* fc_b  = (const float*)d_in[6];

    float* G   = (float*)d_out;                    // B*S*S
    float* Mij = (float*)d_out + BB * SS * SS;     // B*S*S

    float* dx1 = (float*)d_ws;                     // B*S
    float* dx2 = dx1 + BB * SS;                    // B*S

    void* args[] = {(void*)&ctx, (void*)&ln_g, (void*)&ln_b, (void*)&fc_w,
                    (void*)&prior, (void*)&fc_b, (void*)&G, (void*)&Mij,
                    (void*)&dx1, (void*)&dx2};
    hipLaunchCooperativeKernel((void*)fused_kernel, dim3(BB * SS), dim3(SS),
                               args, 0, stream);
}

// Round 3
// 28.862 us; speedup vs baseline: 2.0744x; 2.0744x over previous
//
#include <hip/hip_runtime.h>
#include <math.h>

#define BB 2
#define SS 256
#define DD 256
#define EPSF 1e-6f
#define NT 1024                  // 16 waves per block
#define RPB 16                   // phase-B rows per block
#define NBLK (BB * (SS / RPB))   // 32 blocks

__device__ __forceinline__ float wave_sum(float v) {
#pragma unroll
    for (int o = 32; o > 0; o >>= 1) v += __shfl_xor(v, o);
    return v;
}
__device__ __forceinline__ float wave_scan_sum(float v, int lane) {
#pragma unroll
    for (int o = 1; o < 64; o <<= 1) {
        float u = __shfl_up(v, o);
        if (lane >= o) v += u;
    }
    return v;
}
__device__ __forceinline__ float wave_scan_prod(float v, int lane) {
#pragma unroll
    for (int o = 1; o < 64; o <<= 1) {
        float u = __shfl_up(v, o);
        if (lane >= o) v *= u;
    }
    return v;
}

__global__ __launch_bounds__(NT) void fused1(
        const float* __restrict__ ctx,
        const float* __restrict__ ln_g, const float* __restrict__ ln_b,
        const float* __restrict__ fc_w, const float* __restrict__ prior,
        const float* __restrict__ fc_b,
        float* __restrict__ G, float* __restrict__ Mij) {
    __shared__ float gw1[DD], gw2[DD];
    __shared__ float dx1s[SS], dx2s[SS], P2s[SS];
    __shared__ float parts[4];
    __shared__ float consts[4];   // SG1, SG2, CB1, CB2

    const int t = threadIdx.x;
    const int wv = t >> 6, lane = t & 63;
    const int blk = blockIdx.x;
    const int b  = blk / (SS / RPB);
    const int i0 = (blk % (SS / RPB)) * RPB;

    // stage ln_g*w1, ln_g*w2 in LDS
    if (t < DD) {
        const float g = ln_g[t];
        gw1[t] = g * fc_w[t];
        gw2[t] = g * fc_w[DD + t];
    }
    __syncthreads();

    // wave 0: row-independent constants
    if (wv == 0) {
        float sg1 = 0, sg2 = 0, cb1 = 0, cb2 = 0;
#pragma unroll
        for (int j = 0; j < 4; ++j) {
            const int d = lane + 64 * j;
            sg1 += gw1[d];
            sg2 += gw2[d];
            const float bb = ln_b[d];
            cb1 += bb * fc_w[d];
            cb2 += bb * fc_w[DD + d];
        }
        sg1 = wave_sum(sg1); sg2 = wave_sum(sg2);
        cb1 = wave_sum(cb1); cb2 = wave_sum(cb2);
        if (lane == 0) { consts[0] = sg1; consts[1] = sg2; consts[2] = cb1; consts[3] = cb2; }
    }
    __syncthreads();

    const float SG1 = consts[0], SG2 = consts[1];
    const float CB1 = consts[2], CB2 = consts[3];

    // ---- Phase A (recomputed per block): per-row LN dots -> dx1s/dx2s ----
    const float4* gw14 = (const float4*)gw1;
    const float4* gw24 = (const float4*)gw2;
    const float4  g1 = gw14[lane], g2 = gw24[lane];
#pragma unroll 1
    for (int j = 0; j < SS / 16; ++j) {
        const int k = wv * (SS / 16) + j;
        const float4 c = ((const float4*)(ctx + (size_t)(b * SS + k) * DD))[lane];
        float s0 = c.x + c.y + c.z + c.w;
        float s1 = c.x * c.x + c.y * c.y + c.z * c.z + c.w * c.w;
        float a1 = c.x * g1.x + c.y * g1.y + c.z * g1.z + c.w * g1.w;
        float a2 = c.x * g2.x + c.y * g2.y + c.z * g2.z + c.w * g2.w;
        s0 = wave_sum(s0); s1 = wave_sum(s1);
        a1 = wave_sum(a1); a2 = wave_sum(a2);
        if (lane == 0) {
            const float mu  = s0 * (1.0f / DD);
            const float var = (s1 - DD * mu * mu) * (1.0f / (DD - 1));
            const float inv = 1.0f / (sqrtf(var) + EPSF);
            dx1s[k] = (a1 - mu * SG1) * inv + CB1;
            dx2s[k] = (a2 - mu * SG2) * inv + CB2;
        }
    }
    __syncthreads();

    // ---- scan dx2s -> P2s (inclusive), threads 0..255 only ----
    float incl = 0.0f;
    if (t < SS) {
        incl = wave_scan_sum(dx2s[t], lane);
        if (lane == 63) parts[wv] = incl;
    }
    __syncthreads();
    if (t < SS) {
        float pre = 0.0f;
#pragma unroll
        for (int j = 0; j < 3; ++j)
            if (wv > j) pre += parts[j];
        P2s[t] = incl + pre;
    }
    __syncthreads();

    // ---- Phase B: wave wv -> row i = i0+wv ----
    const float pr = prior[0], fb = fc_b[0];
    const float mconst = pr + (1.0f - pr) / (1.0f + expf(-fb));
    const int i = i0 + wv;
    const float base = (i > 0) ? P2s[i - 1] : 0.0f;
    float carry = 1.0f;
    float* Grow = G   + (size_t)(b * SS + i) * SS;
    float* Mrow = Mij + (size_t)(b * SS + i) * SS;
#pragma unroll
    for (int cc = 0; cc < 4; ++cc) {
        const int k = cc * 64 + lane;
        float m;
        if (k >= i) {
            const float l2 = dx1s[k] + (P2s[k] - base) / (float)(k - i + 1) + fb;
            m = pr + (1.0f - pr) / (1.0f + expf(-l2));
        } else {
            m = mconst;
        }
        Mrow[k] = m;
        const float v = (k >= i) ? m : 1.0f;
        const float p = wave_scan_prod(v, lane) * carry;
        carry = __shfl(p, 63);
        if (k == i) {
            Grow[k] = 1.0f;
        } else if (k > i) {
            Grow[k] = p;                                  // upper triangle, coalesced
            G[(size_t)(b * SS + k) * SS + i] = p;         // symmetric, scattered
        }
    }
}

extern "C" void kernel_launch(void* const* d_in, const int* in_sizes, int n_in,
                              void* d_out, int out_size, void* d_ws, size_t ws_size,
                              hipStream_t stream) {
    const float* ctx   = (const float*)d_in[0];
    // d_in[1] = eos_mask (unused by reference)
    const float* prior = (const float*)d_in[2];
    const float* ln_g  = (const float*)d_in[3];
    const float* ln_b  = (const float*)d_in[4];
    const float* fc_w  = (const float*)d_in[5];
    const float* fc_b  = (const float*)d_in[6];

    float* G   = (float*)d_out;                    // B*S*S
    float* Mij = (float*)d_out + BB * SS * SS;     // B*S*S

    fused1<<<NBLK, NT, 0, stream>>>(ctx, ln_g, ln_b, fc_w, prior, fc_b, G, Mij);
}

// Round 4
// 12.936 us; speedup vs baseline: 4.6283x; 2.2311x over previous
//
#include <hip/hip_runtime.h>
#include <math.h>

#define BB 2
#define SS 256
#define DD 256
#define EPSF 1e-6f

__device__ __forceinline__ float wave_scan_sum(float v, int lane) {
#pragma unroll
    for (int o = 1; o < 64; o <<= 1) {
        float u = __shfl_up(v, o);
        if (lane >= o) v += u;
    }
    return v;
}
__device__ __forceinline__ float wave_scan_prod(float v, int lane) {
#pragma unroll
    for (int o = 1; o < 64; o <<= 1) {
        float u = __shfl_up(v, o);
        if (lane >= o) v *= u;
    }
    return v;
}

// K1: one wave per row. 8 interleaved wave reductions (ILP hides shfl latency).
__global__ __launch_bounds__(256) void k1_lndots(
        const float* __restrict__ ctx,
        const float* __restrict__ ln_g, const float* __restrict__ ln_b,
        const float* __restrict__ fc_w,
        float* __restrict__ dx1, float* __restrict__ dx2) {
    const int t = threadIdx.x, wv = t >> 6, lane = t & 63;
    const int r = blockIdx.x * 4 + wv;            // 128 blocks * 4 waves = 512 rows

    const float4 c  = ((const float4*)ctx)[r * 64 + lane];
    const float4 g  = ((const float4*)ln_g)[lane];
    const float4 bb = ((const float4*)ln_b)[lane];
    const float4 w1 = ((const float4*)fc_w)[lane];
    const float4 w2 = ((const float4*)fc_w)[64 + lane];

    const float gw1x = g.x * w1.x, gw1y = g.y * w1.y, gw1z = g.z * w1.z, gw1w = g.w * w1.w;
    const float gw2x = g.x * w2.x, gw2y = g.y * w2.y, gw2z = g.z * w2.z, gw2w = g.w * w2.w;

    float s0  = c.x + c.y + c.z + c.w;
    float s1  = c.x * c.x + c.y * c.y + c.z * c.z + c.w * c.w;
    float a1  = c.x * gw1x + c.y * gw1y + c.z * gw1z + c.w * gw1w;
    float a2  = c.x * gw2x + c.y * gw2y + c.z * gw2z + c.w * gw2w;
    float sg1 = gw1x + gw1y + gw1z + gw1w;
    float sg2 = gw2x + gw2y + gw2z + gw2w;
    float cb1 = bb.x * w1.x + bb.y * w1.y + bb.z * w1.z + bb.w * w1.w;
    float cb2 = bb.x * w2.x + bb.y * w2.y + bb.z * w2.z + bb.w * w2.w;

#pragma unroll
    for (int o = 32; o > 0; o >>= 1) {            // 8 reductions interleaved
        s0  += __shfl_xor(s0, o);
        s1  += __shfl_xor(s1, o);
        a1  += __shfl_xor(a1, o);
        a2  += __shfl_xor(a2, o);
        sg1 += __shfl_xor(sg1, o);
        sg2 += __shfl_xor(sg2, o);
        cb1 += __shfl_xor(cb1, o);
        cb2 += __shfl_xor(cb2, o);
    }

    if (lane == 0) {
        const float mu  = s0 * (1.0f / DD);
        const float var = (s1 - DD * mu * mu) * (1.0f / (DD - 1));
        const float inv = 1.0f / (sqrtf(var) + EPSF);
        dx1[r] = (a1 - mu * sg1) * inv + cb1;
        dx2[r] = (a2 - mu * sg2) * inv + cb2;
    }
}

// K2: block = output row (b,i). Local scan of dx2 (L2-hot), Mij, product scan, G.
__global__ __launch_bounds__(256) void k2_mg(
        const float* __restrict__ dx1, const float* __restrict__ dx2,
        const float* __restrict__ prior, const float* __restrict__ fc_b,
        float* __restrict__ G, float* __restrict__ Mij) {
    __shared__ float P2s[SS];
    __shared__ float parts_s[4];
    __shared__ float parts_p[4];

    const int r = blockIdx.x;                     // b*S + i
    const int b = r >> 8, i = r & 255;
    const int t = threadIdx.x, wv = t >> 6, lane = t & 63;

    const float d2 = dx2[b * SS + t];
    const float d1 = dx1[b * SS + t];

    // block-wide inclusive sum scan of d2
    float incl = wave_scan_sum(d2, lane);
    if (lane == 63) parts_s[wv] = incl;
    __syncthreads();
#pragma unroll
    for (int j = 0; j < 3; ++j)
        if (wv > j) incl += parts_s[j];
    P2s[t] = incl;
    __syncthreads();

    const float base = (i > 0) ? P2s[i - 1] : 0.0f;
    const float pr = prior[0], fb = fc_b[0];

    float m;
    if (t >= i) {
        const float l = d1 + (incl - base) / (float)(t - i + 1) + fb;
        m = pr + (1.0f - pr) / (1.0f + expf(-l));
    } else {
        m = pr + (1.0f - pr) / (1.0f + expf(-fb));
    }
    Mij[r * SS + t] = m;

    // block-wide inclusive product scan of v
    const float v = (t >= i) ? m : 1.0f;
    float pincl = wave_scan_prod(v, lane);
    if (lane == 63) parts_p[wv] = pincl;
    __syncthreads();
#pragma unroll
    for (int j = 0; j < 3; ++j)
        if (wv > j) pincl *= parts_p[j];

    if (t == i) {
        G[r * SS + t] = 1.0f;
    } else if (t > i) {
        G[r * SS + t] = pincl;                        // row write, coalesced
        G[(size_t)(b * SS + t) * SS + i] = pincl;     // symmetric column write
    }
}

extern "C" void kernel_launch(void* const* d_in, const int* in_sizes, int n_in,
                              void* d_out, int out_size, void* d_ws, size_t ws_size,
                              hipStream_t stream) {
    const float* ctx   = (const float*)d_in[0];
    // d_in[1] = eos_mask (unused by reference)
    const float* prior = (const float*)d_in[2];
    const float* ln_g  = (const float*)d_in[3];
    const float* ln_b  = (const float*)d_in[4];
    const float* fc_w  = (const float*)d_in[5];
    const float* fc_b  = (const float*)d_in[6];

    float* G   = (float*)d_out;                    // B*S*S
    float* Mij = (float*)d_out + BB * SS * SS;     // B*S*S

    float* dx1 = (float*)d_ws;                     // B*S
    float* dx2 = dx1 + BB * SS;                    // B*S

    k1_lndots<<<BB * SS / 4, 256, 0, stream>>>(ctx, ln_g, ln_b, fc_w, dx1, dx2);
    k2_mg<<<BB * SS, 256, 0, stream>>>(dx1, dx2, prior, fc_b, G, Mij);
}